// Round 1
// baseline (954.786 us; speedup 1.0000x reference)
//
#include <hip/hip_runtime.h>
#include <math.h>

#define NEXP 48
#define NCAT 30
#define SP_TOT 13440            // 24*28*20
#define M_TOT (NCAT * SP_TOT)   // 403200

// Kernel 1: per voxel-column top-K (|value|, stable tie-break) + contraction.
// One thread per column m in [0, M_TOT); handles both gating tensors.
__global__ __launch_bounds__(256) void moe_topk_contract(
    const float* __restrict__ gm, const float* __restrict__ gf,
    const float* __restrict__ se, const int* __restrict__ kptr,
    float* __restrict__ out)
{
    const int m = blockIdx.x * blockDim.x + threadIdx.x;
    if (m >= M_TOT) return;
    const int K = *kptr;

    #pragma unroll 1
    for (int t = 0; t < 2; ++t) {
        const float* __restrict__ g_ = (t == 0) ? gm : gf;

        float g[NEXP];
        int   r[NEXP];
        #pragma unroll
        for (int k = 0; k < NEXP; ++k) {
            g[k] = g_[k * M_TOT + m];
            r[k] = 0;
        }

        // Pairwise rank: r[i] = #{j: |g_j| > |g_i|} + #{j<i: |g_j| == |g_i|}
        // (exactly matches jax.lax.top_k stable tie-breaking).
        #pragma unroll
        for (int i = 0; i < NEXP - 1; ++i) {
            #pragma unroll
            for (int j = i + 1; j < NEXP; ++j) {
                const bool c = fabsf(g[i]) >= fabsf(g[j]);  // tie -> lower index wins
                r[j] += c;
                r[i] += !c;
            }
        }

        float acc = 0.f;
        #pragma unroll
        for (int k = 0; k < NEXP; ++k) {
            const float s = se[k * M_TOT + m];
            acc = (r[k] < K) ? fmaf(g[k], s, acc) : acc;
        }
        out[t * M_TOT + m] = acc;
    }
}

// Kernel 2: in-place softmax over the category dim (stride SP_TOT) of d_out.
// One thread per (tensor, spatial) column; each thread owns its 30 elements.
__global__ __launch_bounds__(256) void softmax_c(float* __restrict__ out)
{
    const int q = blockIdx.x * blockDim.x + threadIdx.x;
    if (q >= 2 * SP_TOT) return;
    const int t  = q / SP_TOT;
    const int sp = q - t * SP_TOT;
    float* __restrict__ base = out + t * M_TOT + sp;

    float v[NCAT];
    float mx = -INFINITY;
    #pragma unroll
    for (int c = 0; c < NCAT; ++c) {
        v[c] = base[c * SP_TOT];
        mx = fmaxf(mx, v[c]);
    }
    float sum = 0.f;
    #pragma unroll
    for (int c = 0; c < NCAT; ++c) {
        v[c] = __expf(v[c] - mx);
        sum += v[c];
    }
    const float inv = 1.f / sum;
    #pragma unroll
    for (int c = 0; c < NCAT; ++c) {
        base[c * SP_TOT] = v[c] * inv;
    }
}

extern "C" void kernel_launch(void* const* d_in, const int* in_sizes, int n_in,
                              void* d_out, int out_size, void* d_ws, size_t ws_size,
                              hipStream_t stream) {
    const float* gm   = (const float*)d_in[0];
    const float* gf   = (const float*)d_in[1];
    const float* se   = (const float*)d_in[2];
    const int*   kptr = (const int*)d_in[3];
    float* out = (float*)d_out;

    const int threads = 256;
    const int grid1 = (M_TOT + threads - 1) / threads;      // 1575
    moe_topk_contract<<<grid1, threads, 0, stream>>>(gm, gf, se, kptr, out);

    const int grid2 = (2 * SP_TOT + threads - 1) / threads; // 105
    softmax_c<<<grid2, threads, 0, stream>>>(out);
}

// Round 2
// 119.307 us; speedup vs baseline: 8.0028x; 8.0028x over previous
//
#include <hip/hip_runtime.h>
#include <math.h>
#include <stdint.h>

#define NEXP 48
#define NCAT 30
#define SP_TOT 13440            // 24*28*20
#define M_TOT (NCAT * SP_TOT)   // 403200
#define COLS_PER_BLOCK 32
#define PADK 49                 // padded expert dim in LDS (bank decorrelation)

// Kernel 1: cooperative top-K + contraction.
// 8 threads per column; each owns 6 experts (static reg arrays).
// Ranks via u64 keys in LDS: key = (abs_bits<<32) | (47-e)  -> strict u64 '>'
// reproduces jax.lax.top_k's stable by-|value|, lower-index-wins ordering.
__global__ __launch_bounds__(256) void moe_topk_contract(
    const float* __restrict__ gm, const float* __restrict__ gf,
    const float* __restrict__ se, const int* __restrict__ kptr,
    float* __restrict__ out)
{
    __shared__ uint64_t keys[COLS_PER_BLOCK * PADK];
    __shared__ float    gval[COLS_PER_BLOCK * PADK];

    const int tid       = threadIdx.x;
    const int colbase   = blockIdx.x * COLS_PER_BLOCK;
    const int col_local = tid >> 3;   // 0..31
    const int sub       = tid & 7;    // 0..7
    const int col       = colbase + col_local;
    const int K         = *kptr;

    // shape_experts values for this thread's 6 experts (t-invariant)
    float se_own[6];
    #pragma unroll
    for (int ii = 0; ii < 6; ++ii)
        se_own[ii] = se[(sub * 6 + ii) * M_TOT + col];

    #pragma unroll 1
    for (int t = 0; t < 2; ++t) {
        const float* __restrict__ g_ = t ? gf : gm;

        // stage 48 experts x 32 cols: 256 threads, 6 coalesced elems each
        #pragma unroll
        for (int rep = 0; rep < 6; ++rep) {
            const int e = rep * 8 + (tid >> 5);  // 0..47
            const int c = tid & 31;
            const float v = g_[e * M_TOT + colbase + c];
            const uint32_t ab = __float_as_uint(v) & 0x7fffffffu;
            keys[c * PADK + e] = ((uint64_t)ab << 32) | (uint32_t)(NEXP - 1 - e);
            gval[c * PADK + e] = v;
        }
        __syncthreads();

        uint64_t kown[6];
        float    gown[6];
        int      r[6];
        #pragma unroll
        for (int ii = 0; ii < 6; ++ii) {
            kown[ii] = keys[col_local * PADK + sub * 6 + ii];
            gown[ii] = gval[col_local * PADK + sub * 6 + ii];
            r[ii] = 0;
        }

        // rank = #{j : key_j > key_i}; self-compare contributes 0
        #pragma unroll
        for (int j = 0; j < NEXP; ++j) {
            const uint64_t kj = keys[col_local * PADK + j];
            #pragma unroll
            for (int ii = 0; ii < 6; ++ii)
                r[ii] += (kj > kown[ii]) ? 1 : 0;
        }

        float acc = 0.f;
        #pragma unroll
        for (int ii = 0; ii < 6; ++ii)
            acc = (r[ii] < K) ? fmaf(gown[ii], se_own[ii], acc) : acc;

        // reduce across the 8 threads of this column (low 3 lane bits)
        acc += __shfl_xor(acc, 1);
        acc += __shfl_xor(acc, 2);
        acc += __shfl_xor(acc, 4);
        if (sub == 0) out[t * M_TOT + col] = acc;
        __syncthreads();
    }
}

// Kernel 2: in-place softmax over the category dim (stride SP_TOT).
__global__ __launch_bounds__(256) void softmax_c(float* __restrict__ out)
{
    const int q = blockIdx.x * blockDim.x + threadIdx.x;
    if (q >= 2 * SP_TOT) return;
    const int t  = q / SP_TOT;
    const int sp = q - t * SP_TOT;
    float* __restrict__ base = out + t * M_TOT + sp;

    float v[NCAT];
    float mx = -INFINITY;
    #pragma unroll
    for (int c = 0; c < NCAT; ++c) {
        v[c] = base[c * SP_TOT];
        mx = fmaxf(mx, v[c]);
    }
    float sum = 0.f;
    #pragma unroll
    for (int c = 0; c < NCAT; ++c) {
        v[c] = __expf(v[c] - mx);
        sum += v[c];
    }
    const float inv = 1.f / sum;
    #pragma unroll
    for (int c = 0; c < NCAT; ++c)
        base[c * SP_TOT] = v[c] * inv;
}

extern "C" void kernel_launch(void* const* d_in, const int* in_sizes, int n_in,
                              void* d_out, int out_size, void* d_ws, size_t ws_size,
                              hipStream_t stream) {
    const float* gm   = (const float*)d_in[0];
    const float* gf   = (const float*)d_in[1];
    const float* se   = (const float*)d_in[2];
    const int*   kptr = (const int*)d_in[3];
    float* out = (float*)d_out;

    const int grid1 = M_TOT / COLS_PER_BLOCK;               // 12600
    moe_topk_contract<<<grid1, 256, 0, stream>>>(gm, gf, se, kptr, out);

    const int grid2 = (2 * SP_TOT + 255) / 256;             // 105
    softmax_c<<<grid2, 256, 0, stream>>>(out);
}